// Round 2
// baseline (692.221 us; speedup 1.0000x reference)
//
#include <hip/hip_runtime.h>
#include <hip/hip_bf16.h>

// Problem dims (fixed by the reference)
#define Td 4096   // tokens
#define Hd 1024   // hidden
#define Fd 4096   // ffn
#define Ed 8      // experts
#define Rcap 9216 // 72*128 compacted-row capacity (>= 8192 + 8*127, padded to 128)

typedef __attribute__((ext_vector_type(8))) short bf16x8;   // MFMA A/B frag (4 VGPRs)
typedef __attribute__((ext_vector_type(4))) float f32x4;    // MFMA C/D frag
typedef __attribute__((ext_vector_type(8))) unsigned short u16x8;

__device__ __forceinline__ unsigned short f32_to_bf16(float x) {
  unsigned int u = __float_as_uint(x);
  unsigned int r = (u + 0x7FFFu + ((u >> 16) & 1u)) >> 16;
  return (unsigned short)r;
}

// async global->LDS, 16B per lane. LDS dest is wave-uniform base + lane*16.
__device__ __forceinline__ void gload_lds16(const unsigned short* g, unsigned short* l) {
  __builtin_amdgcn_global_load_lds(
      (const __attribute__((address_space(1))) unsigned int*)g,
      (__attribute__((address_space(3))) unsigned int*)l, 16, 0, 0);
}

// ---------------- hidden f32 -> bf16 ----------------
__global__ __launch_bounds__(256) void cvt_bf16_kernel(const float* __restrict__ in,
                                                       unsigned short* __restrict__ outp, int n8) {
  int i = blockIdx.x * 256 + threadIdx.x;
  if (i >= n8) return;
  const float4* p = (const float4*)(in + (size_t)i * 8);
  float4 a = p[0], b = p[1];
  u16x8 o;
  o[0] = f32_to_bf16(a.x); o[1] = f32_to_bf16(a.y); o[2] = f32_to_bf16(a.z); o[3] = f32_to_bf16(a.w);
  o[4] = f32_to_bf16(b.x); o[5] = f32_to_bf16(b.y); o[6] = f32_to_bf16(b.z); o[7] = f32_to_bf16(b.w);
  *(u16x8*)(outp + (size_t)i * 8) = o;
}

// ---------------- weight transpose+convert: in [E][Rd][Cd] f32 -> out [E][Cd][Rd] bf16 ----------------
__global__ __launch_bounds__(256) void transpose_cvt_kernel(const float* __restrict__ in,
                                                            unsigned short* __restrict__ outp,
                                                            int Rdm, int Cdm) {
  __shared__ float tile[64][68];  // 68 stride: keeps float4 LDS stores 16B-aligned
  int tilesR = Rdm >> 6, tilesC = Cdm >> 6;
  int per = tilesR * tilesC;
  int bid = blockIdx.x;
  int e = bid / per; int rem = bid - e * per;
  int tr = rem / tilesC; int tc = rem - tr * tilesC;
  int r0 = tr << 6, c0 = tc << 6;
  int tid = threadIdx.x;
  int rr = tid >> 2, cq = (tid & 3) << 4;
  const float* src = in + ((size_t)e * Rdm + r0 + rr) * Cdm + c0 + cq;
  float4 v0 = ((const float4*)src)[0];
  float4 v1 = ((const float4*)src)[1];
  float4 v2 = ((const float4*)src)[2];
  float4 v3 = ((const float4*)src)[3];
  *(float4*)&tile[rr][cq + 0]  = v0;
  *(float4*)&tile[rr][cq + 4]  = v1;
  *(float4*)&tile[rr][cq + 8]  = v2;
  *(float4*)&tile[rr][cq + 12] = v3;
  __syncthreads();
  // out row (c0+rr), k-range [r0+cq, +16): coalesced 16B x2 stores
  u16x8 o0, o1;
#pragma unroll
  for (int j = 0; j < 8; j++) o0[j] = f32_to_bf16(tile[cq + j][rr]);
#pragma unroll
  for (int j = 0; j < 8; j++) o1[j] = f32_to_bf16(tile[cq + 8 + j][rr]);
  unsigned short* dst = outp + ((size_t)e * Cdm + c0 + rr) * Rdm + r0 + cq;
  *(u16x8*)dst = o0;
  *(u16x8*)(dst + 8) = o1;
}

// ---------------- routing ----------------
__global__ void init_meta_kernel(int* cnt) {
  if (threadIdx.x < Ed) cnt[threadIdx.x] = 0;
}

__global__ __launch_bounds__(256) void route_kernel(const int* __restrict__ sel,
                                                    const float* __restrict__ ew,
                                                    int* cnt, int* idxT, float* wgtT) {
  int t = blockIdx.x * 256 + threadIdx.x;
  if (t >= Td) return;
  int e0 = sel[t * 2], e1 = sel[t * 2 + 1];
  float w0 = ew[t * 2], w1 = ew[t * 2 + 1];
  if (e0 == e1) { w0 += w1; e1 = -1; }   // merge duplicate expert: one entry, summed weight
  if (e0 >= 0 && e0 < Ed) { int p = atomicAdd(&cnt[e0], 1); idxT[e0 * Td + p] = t; wgtT[e0 * Td + p] = w0; }
  if (e1 >= 0 && e1 < Ed) { int p = atomicAdd(&cnt[e1], 1); idxT[e1 * Td + p] = t; wgtT[e1 * Td + p] = w1; }
}

__global__ void scan_kernel(const int* cnt, int* off) {
  if (threadIdx.x == 0) {
    int acc = 0; off[0] = 0;
#pragma unroll
    for (int e = 0; e < Ed; e++) { acc += (cnt[e] + 127) & ~127; off[e + 1] = acc; }
  }
}

__global__ __launch_bounds__(256) void compact_kernel(const int* __restrict__ cnt,
                                                      const int* __restrict__ off,
                                                      const int* __restrict__ idxT,
                                                      const float* __restrict__ wgtT,
                                                      int* __restrict__ cidx,
                                                      float* __restrict__ cwgt) {
  int j = blockIdx.x * 256 + threadIdx.x;  // j in [0, Ed*Td)
  int e = j >> 12; int i = j & (Td - 1);
  int base = off[e], end = off[e + 1];
  int row = base + i;
  if (row < end) {
    if (i < cnt[e]) { cidx[row] = idxT[e * Td + i]; cwgt[row] = wgtT[e * Td + i]; }
    else            { cidx[row] = -1;               cwgt[row] = 0.f; }
  }
}

// ---------------- m97-class MFMA GEMM: BM=128, BK=64, 4 waves (2x2), global_load_lds w16 ----------------
// FIRST:  A = hbf[T][Hd] gathered by cidx, B = W1T[e][Fd][Hd], out = gelu(A*B + b1) -> hbuf (bf16)
// !FIRST: A = hbuf rows,                  B = W2T[e][Hd][Fd], out[t] += cw * (A*B + b2) (atomic f32)
template <bool FIRST, int KD, int NC, int BN>
__global__ __launch_bounds__(256) void gemm_kernel(const unsigned short* __restrict__ Abase,
                                                   const unsigned short* __restrict__ Bt,
                                                   const float* __restrict__ bias,
                                                   const int* __restrict__ cidx,
                                                   const float* __restrict__ cwgt,
                                                   const int* __restrict__ off,
                                                   unsigned short* __restrict__ hbuf,
                                                   float* __restrict__ outp) {
  constexpr int NF = BN / 32;            // n-frags per wave (wave owns 64 x BN/2)
  int row0 = blockIdx.x << 7;
  int tot = off[Ed];
  if (row0 >= tot) return;               // tot is a multiple of 128: no partial tiles
  int e = 0;
  while (off[e + 1] <= row0) ++e;        // 128-padded offsets: tile never spans experts
  int n0 = blockIdx.y * BN;

  __shared__ unsigned short As[128][64]; // linear (global_load_lds requires it); 16KB
  __shared__ unsigned short Bs[BN][64];  // 16KB (BN=128) or 8KB (BN=64)

  const int tid = threadIdx.x;
  const int lane = tid & 63, w = tid >> 6;
  const int wr = w >> 1, wc = w & 1;     // 2x2 wave grid
  const int fr = lane & 15, fk = (lane >> 4) << 3;

  // ---- staging addresses: per global_load_lds inst, a wave moves 8 rows x 128B ----
  const int sofs = (lane & 7) << 3;      // k-element offset within row (16B chunks)
  const unsigned short* aptr[4];
#pragma unroll
  for (int i = 0; i < 4; i++) {
    int ar = (w << 5) + (i << 3) + (lane >> 3);           // 0..127
    int t;
    if (FIRST) { t = cidx[row0 + ar]; if (t < 0) t = 0; } // clamp: garbage confined to dead rows
    else       { t = row0 + ar; }
    aptr[i] = Abase + (size_t)t * KD + sofs;
  }
  const unsigned short* bptr[NF];
#pragma unroll
  for (int i = 0; i < NF; i++) {
    int br = w * (BN / 4) + (i << 3) + (lane >> 3);       // 0..BN-1
    bptr[i] = Bt + ((size_t)e * NC + n0 + br) * KD + sofs;
  }
  unsigned short* alds = &As[0][0] + (w << 11);           // wave base: w*4096 bytes
  unsigned short* blds = &Bs[0][0] + w * (BN * 16);       // wave base: w*(BN*32) bytes

  f32x4 acc[4][NF] = {};

  for (int k0 = 0; k0 < KD; k0 += 64) {
    __syncthreads();                     // all waves done reading LDS from prev iter
#pragma unroll
    for (int i = 0; i < 4; i++)  gload_lds16(aptr[i] + k0, alds + (i << 9));
#pragma unroll
    for (int i = 0; i < NF; i++) gload_lds16(bptr[i] + k0, blds + (i << 9));
    __syncthreads();                     // compiler drains vmcnt(0) before barrier
#pragma unroll
    for (int ks = 0; ks < 64; ks += 32) {
      bf16x8 af[4], bg[NF];
#pragma unroll
      for (int mi = 0; mi < 4; mi++)
        af[mi] = *(const bf16x8*)&As[(wr << 6) + (mi << 4) + fr][ks + fk];
#pragma unroll
      for (int ni = 0; ni < NF; ni++)
        bg[ni] = *(const bf16x8*)&Bs[wc * (BN / 2) + (ni << 4) + fr][ks + fk];
#pragma unroll
      for (int mi = 0; mi < 4; mi++)
#pragma unroll
        for (int ni = 0; ni < NF; ni++)
          acc[mi][ni] = __builtin_amdgcn_mfma_f32_16x16x32_bf16(af[mi], bg[ni], acc[mi][ni], 0, 0, 0);
    }
  }

  // epilogue — C/D layout (m89-verified): col = lane&15, row = (lane>>4)*4 + reg
  float bv[NF];
#pragma unroll
  for (int ni = 0; ni < NF; ni++) bv[ni] = bias[e * NC + n0 + wc * (BN / 2) + (ni << 4) + fr];
#pragma unroll
  for (int mi = 0; mi < 4; mi++) {
#pragma unroll
    for (int r2 = 0; r2 < 4; r2++) {
      int row = row0 + (wr << 6) + (mi << 4) + ((lane >> 4) << 2) + r2;
      if (FIRST) {
#pragma unroll
        for (int ni = 0; ni < NF; ni++) {
          int col = n0 + wc * (BN / 2) + (ni << 4) + fr;
          float x = acc[mi][ni][r2] + bv[ni];
          float g = 0.5f * x * (1.0f + erff(x * 0.70710678118654752f));  // exact GELU
          hbuf[(size_t)row * NC + col] = f32_to_bf16(g);
        }
      } else {
        int tdst = cidx[row];
        float cw = cwgt[row];
        if (tdst >= 0) {
#pragma unroll
          for (int ni = 0; ni < NF; ni++) {
            int col = n0 + wc * (BN / 2) + (ni << 4) + fr;
            atomicAdd(outp + (size_t)tdst * NC + col, cw * (acc[mi][ni][r2] + bv[ni]));
          }
        }
      }
    }
  }
}

extern "C" void kernel_launch(void* const* d_in, const int* in_sizes, int n_in,
                              void* d_out, int out_size, void* d_ws, size_t ws_size,
                              hipStream_t stream) {
  const float* hidden = (const float*)d_in[0];
  const float* ew     = (const float*)d_in[1];
  const float* W1     = (const float*)d_in[2];
  const float* b1     = (const float*)d_in[3];
  const float* W2     = (const float*)d_in[4];
  const float* b2     = (const float*)d_in[5];
  const int*   sel    = (const int*)d_in[6];
  float* outp = (float*)d_out;

  // workspace layout (~212 MB)
  unsigned short* hbf  = (unsigned short*)d_ws;                  // [T][H] bf16        8 MB
  unsigned short* W1T  = hbf + (size_t)Td * Hd;                  // [E][F][H] bf16    64 MB
  unsigned short* W2T  = W1T + (size_t)Ed * Fd * Hd;             // [E][H][F] bf16    64 MB
  unsigned short* hbuf = W2T + (size_t)Ed * Hd * Fd;             // [Rcap][F] bf16  75.5 MB
  int*   cnt  = (int*)(hbuf + (size_t)Rcap * Fd);
  int*   off  = cnt + 16;
  int*   idxT = off + 16;
  float* wgtT = (float*)(idxT + Ed * Td);
  int*   cidx = (int*)(wgtT + Ed * Td);
  float* cwgt = (float*)(cidx + Rcap);

  (void)hipMemsetAsync(d_out, 0, (size_t)Td * Hd * sizeof(float), stream);

  cvt_bf16_kernel<<<(Td * Hd / 8 + 255) / 256, 256, 0, stream>>>(hidden, hbf, Td * Hd / 8);
  transpose_cvt_kernel<<<Ed * (Hd / 64) * (Fd / 64), 256, 0, stream>>>(W1, W1T, Hd, Fd);
  transpose_cvt_kernel<<<Ed * (Fd / 64) * (Hd / 64), 256, 0, stream>>>(W2, W2T, Fd, Hd);

  init_meta_kernel<<<1, 64, 0, stream>>>(cnt);
  route_kernel<<<Td / 256, 256, 0, stream>>>(sel, ew, cnt, idxT, wgtT);
  scan_kernel<<<1, 64, 0, stream>>>(cnt, off);
  compact_kernel<<<Ed * Td / 256, 256, 0, stream>>>(cnt, off, idxT, wgtT, cidx, cwgt);

  gemm_kernel<true, Hd, Fd, 128><<<dim3(Rcap / 128, Fd / 128), 256, 0, stream>>>(
      hbf, W1T, b1, cidx, cwgt, off, hbuf, nullptr);
  gemm_kernel<false, Fd, Hd, 64><<<dim3(Rcap / 128, Hd / 64), 256, 0, stream>>>(
      hbuf, W2T, b2, cidx, cwgt, off, nullptr, outp);
}

// Round 3
// 658.788 us; speedup vs baseline: 1.0507x; 1.0507x over previous
//
#include <hip/hip_runtime.h>
#include <hip/hip_bf16.h>

// Problem dims (fixed by the reference)
#define Td 4096   // tokens
#define Hd 1024   // hidden
#define Fd 4096   // ffn
#define Ed 8      // experts
#define Rcap 10240 // 40*256 compacted-row capacity (>= 8192 + 8*255, padded to 256)

typedef __attribute__((ext_vector_type(8))) short bf16x8;   // MFMA A/B frag (4 VGPRs)
typedef __attribute__((ext_vector_type(4))) float f32x4;    // MFMA C/D frag
typedef __attribute__((ext_vector_type(8))) unsigned short u16x8;

__device__ __forceinline__ unsigned short f32_to_bf16(float x) {
  unsigned int u = __float_as_uint(x);
  unsigned int r = (u + 0x7FFFu + ((u >> 16) & 1u)) >> 16;
  return (unsigned short)r;
}

// async global->LDS, 16B per lane. LDS dest is wave-uniform base + lane*16.
__device__ __forceinline__ void gload_lds16(const unsigned short* g, unsigned short* l) {
  __builtin_amdgcn_global_load_lds(
      (const __attribute__((address_space(1))) unsigned int*)g,
      (__attribute__((address_space(3))) unsigned int*)l, 16, 0, 0);
}

// ---------------- hidden f32 -> bf16 ----------------
__global__ __launch_bounds__(256) void cvt_bf16_kernel(const float* __restrict__ in,
                                                       unsigned short* __restrict__ outp, int n8) {
  int i = blockIdx.x * 256 + threadIdx.x;
  if (i >= n8) return;
  const float4* p = (const float4*)(in + (size_t)i * 8);
  float4 a = p[0], b = p[1];
  u16x8 o;
  o[0] = f32_to_bf16(a.x); o[1] = f32_to_bf16(a.y); o[2] = f32_to_bf16(a.z); o[3] = f32_to_bf16(a.w);
  o[4] = f32_to_bf16(b.x); o[5] = f32_to_bf16(b.y); o[6] = f32_to_bf16(b.z); o[7] = f32_to_bf16(b.w);
  *(u16x8*)(outp + (size_t)i * 8) = o;
}

// ---------------- weight transpose+convert: in [E][Rd][Cd] f32 -> out [E][Cd][Rd] bf16 ----------------
__global__ __launch_bounds__(256) void transpose_cvt_kernel(const float* __restrict__ in,
                                                            unsigned short* __restrict__ outp,
                                                            int Rdm, int Cdm) {
  __shared__ float tile[64][68];
  int tilesR = Rdm >> 6, tilesC = Cdm >> 6;
  int per = tilesR * tilesC;
  int bid = blockIdx.x;
  int e = bid / per; int rem = bid - e * per;
  int tr = rem / tilesC; int tc = rem - tr * tilesC;
  int r0 = tr << 6, c0 = tc << 6;
  int tid = threadIdx.x;
  int rr = tid >> 2, cq = (tid & 3) << 4;
  const float* src = in + ((size_t)e * Rdm + r0 + rr) * Cdm + c0 + cq;
  float4 v0 = ((const float4*)src)[0];
  float4 v1 = ((const float4*)src)[1];
  float4 v2 = ((const float4*)src)[2];
  float4 v3 = ((const float4*)src)[3];
  *(float4*)&tile[rr][cq + 0]  = v0;
  *(float4*)&tile[rr][cq + 4]  = v1;
  *(float4*)&tile[rr][cq + 8]  = v2;
  *(float4*)&tile[rr][cq + 12] = v3;
  __syncthreads();
  u16x8 o0, o1;
#pragma unroll
  for (int j = 0; j < 8; j++) o0[j] = f32_to_bf16(tile[cq + j][rr]);
#pragma unroll
  for (int j = 0; j < 8; j++) o1[j] = f32_to_bf16(tile[cq + 8 + j][rr]);
  unsigned short* dst = outp + ((size_t)e * Cdm + c0 + rr) * Rdm + r0 + cq;
  *(u16x8*)dst = o0;
  *(u16x8*)(dst + 8) = o1;
}

// ---------------- routing: single block does count + scan + compact ----------------
__global__ __launch_bounds__(1024) void route_all_kernel(const int* __restrict__ sel,
                                                         const float* __restrict__ ew,
                                                         int* __restrict__ idxT,
                                                         float* __restrict__ wgtT,
                                                         int* __restrict__ off_g,
                                                         int* __restrict__ cidx,
                                                         float* __restrict__ cwgt) {
  __shared__ int cnt[Ed];
  __shared__ int off[Ed + 1];
  int tid = threadIdx.x;
  if (tid < Ed) cnt[tid] = 0;
  __syncthreads();
  for (int t = tid; t < Td; t += 1024) {
    int e0 = sel[2 * t], e1 = sel[2 * t + 1];
    float w0 = ew[2 * t], w1 = ew[2 * t + 1];
    if (e0 == e1) { w0 += w1; e1 = -1; }  // merge duplicate expert
    if (e0 >= 0 && e0 < Ed) { int p = atomicAdd(&cnt[e0], 1); idxT[e0 * Td + p] = t; wgtT[e0 * Td + p] = w0; }
    if (e1 >= 0 && e1 < Ed) { int p = atomicAdd(&cnt[e1], 1); idxT[e1 * Td + p] = t; wgtT[e1 * Td + p] = w1; }
  }
  __syncthreads();
  if (tid == 0) {
    int acc = 0; off[0] = 0;
#pragma unroll
    for (int e = 0; e < Ed; e++) { acc += (cnt[e] + 255) & ~255; off[e + 1] = acc; }
  }
  __syncthreads();
  for (int j = tid; j < Ed * Td; j += 1024) {
    int e = j >> 12, i = j & (Td - 1);
    int row = off[e] + i;
    if (row < off[e + 1]) {
      if (i < cnt[e]) { cidx[row] = idxT[e * Td + i]; cwgt[row] = wgtT[e * Td + i]; }
      else            { cidx[row] = -1;               cwgt[row] = 0.f; }
    }
  }
  if (tid <= Ed) off_g[tid] = off[tid];
}

// ---------------- pipelined MFMA GEMM ----------------
// BM=256, BN=128, BK=64, 8 waves (2x4), wave owns 128x32 (8 m-frags x 2 n-frags).
// LDS: 3 buffers x (A 32KB + B 16KB) = 144 KB. Stage tile t+2 during tile t phase0.
// Counted s_waitcnt vmcnt(6) at tile boundary (t+2's 6 loads in flight, FIFO => t+1 resident).
// T2 XOR swizzle kbyte ^= (row&7)<<4, via inverse-swizzled global source + swizzled ds_read.
// FIRST:  A = hbf gathered by cidx, B = W1T[e][F][H]; out = gelu(A*B + b1) -> hbuf (bf16)
// !FIRST: A = hbuf rows,            B = W2T[e][H][F]; out[t] += cw * (A*B [+ b2 if z==0]) (atomic f32)
template <bool FIRST, int KD, int NC, int KSPLIT>
__global__ __launch_bounds__(512, 2) void gemm_kernel(const unsigned short* __restrict__ Abase,
                                                      const unsigned short* __restrict__ Bt,
                                                      const float* __restrict__ bias,
                                                      const int* __restrict__ cidx,
                                                      const float* __restrict__ cwgt,
                                                      const int* __restrict__ off,
                                                      unsigned short* __restrict__ hbuf,
                                                      float* __restrict__ outp) {
  extern __shared__ unsigned short lds[];   // 3*16384 (A) + 3*8192 (B) elems = 147456 B
  constexpr int KLEN = KD / KSPLIT;
  constexpr int NT = KLEN / 64;

  const int row0 = blockIdx.x << 8;
  const int tot = off[Ed];
  if (row0 >= tot) return;                 // uniform exit, before any barrier
  int e = 0;
  while (off[e + 1] <= row0) ++e;          // 256-padded: tile never spans experts
  const int n0 = blockIdx.y << 7;
  const int kbase = blockIdx.z * KLEN;

  const int tid = threadIdx.x;
  const int lane = tid & 63, w = tid >> 6;
  const int wrow = w >> 2, wcol = w & 3;   // 2x4 wave grid
  const int fr = lane & 15;
  const int fkb = (lane >> 4) << 4;        // frag k-byte sub-offset (0,16,32,48)

  // ---- stage source pointers (inverse-swizzled global so linear LDS dest + swizzled read works) ----
  const unsigned short* aptr[4];
#pragma unroll
  for (int i = 0; i < 4; i++) {
    int r = (i << 6) + (tid >> 3);                         // 0..255
    int kel = ((tid & 7) ^ (r & 7)) << 3;                  // element offset, pre-swizzled
    int g;
    if (FIRST) { g = cidx[row0 + r]; if (g < 0) g = 0; }   // clamp: garbage confined to dead rows
    else       { g = row0 + r; }
    aptr[i] = Abase + (size_t)g * KD + kbase + kel;
  }
  const unsigned short* bptr[2];
#pragma unroll
  for (int i = 0; i < 2; i++) {
    int r = (i << 6) + (tid >> 3);                         // 0..127
    int kel = ((tid & 7) ^ (r & 7)) << 3;
    bptr[i] = Bt + ((size_t)e * NC + n0 + r) * KD + kbase + kel;
  }
  unsigned short* ldsA = lds;              // 3 bufs x 16384 elems
  unsigned short* ldsB = lds + 49152;      // 3 bufs x 8192 elems

  f32x4 acc[8][2] = {};

#define STAGE(t)                                                         \
  {                                                                      \
    int _b = (t) % 3;                                                    \
    int _k0 = (t) << 6;                                                  \
    unsigned short* _la = ldsA + (_b << 14) + (w << 9);                  \
    unsigned short* _lb = ldsB + (_b << 13) + (w << 9);                  \
    _Pragma("unroll")                                                    \
    for (int _i = 0; _i < 4; _i++) gload_lds16(aptr[_i] + _k0, _la + (_i << 12)); \
    _Pragma("unroll")                                                    \
    for (int _i = 0; _i < 2; _i++) gload_lds16(bptr[_i] + _k0, _lb + (_i << 12)); \
  }

  // swizzled ds_read of a frag: logical (row r, kbyte kb) -> physical kb ^ ((r&7)<<4)
#define LDA(dst, buf, m, ks)                                                     \
  {                                                                              \
    int _r = (wrow << 7) + ((m) << 4) + fr;                                      \
    int _p = (((ks) << 6) + fkb) ^ ((_r & 7) << 4);                              \
    dst = *(const bf16x8*)(ldsA + ((buf) << 14) + (_r << 6) + (_p >> 1));        \
  }
#define LDB(dst, buf, nf, ks)                                                    \
  {                                                                              \
    int _r = (wcol << 5) + ((nf) << 4) + fr;                                     \
    int _p = (((ks) << 6) + fkb) ^ ((_r & 7) << 4);                              \
    dst = *(const bf16x8*)(ldsB + ((buf) << 13) + (_r << 6) + (_p >> 1));        \
  }

  // prologue: stage tiles 0,1; wait tile 0 (6 newest outstanding = tile 1's)
  STAGE(0);
  if constexpr (NT > 1) {
    STAGE(1);
    asm volatile("s_waitcnt vmcnt(6)" ::: "memory");
  } else {
    asm volatile("s_waitcnt vmcnt(0)" ::: "memory");
  }
  __builtin_amdgcn_s_barrier();

  for (int t = 0; t < NT; ++t) {
    const int buf = t % 3;
    // ---- phase 0: B frags + A m0-3; stage t+2 ----
    bf16x8 bfr[2][2];
#pragma unroll
    for (int nf = 0; nf < 2; nf++)
#pragma unroll
      for (int ks = 0; ks < 2; ks++) LDB(bfr[nf][ks], buf, nf, ks);
    bf16x8 afr[4][2];
#pragma unroll
    for (int m = 0; m < 4; m++)
#pragma unroll
      for (int ks = 0; ks < 2; ks++) LDA(afr[m][ks], buf, m, ks);
    if (t + 2 < NT) STAGE(t + 2);
    __builtin_amdgcn_s_barrier();
    __builtin_amdgcn_s_setprio(1);
#pragma unroll
    for (int m = 0; m < 4; m++)
#pragma unroll
      for (int nf = 0; nf < 2; nf++)
#pragma unroll
        for (int ks = 0; ks < 2; ks++)
          acc[m][nf] = __builtin_amdgcn_mfma_f32_16x16x32_bf16(afr[m][ks], bfr[nf][ks], acc[m][nf], 0, 0, 0);
    __builtin_amdgcn_s_setprio(0);
    __builtin_amdgcn_s_barrier();
    // ---- phase 1: A m4-7 (reuse B frags) ----
#pragma unroll
    for (int m = 0; m < 4; m++)
#pragma unroll
      for (int ks = 0; ks < 2; ks++) LDA(afr[m][ks], buf, m + 4, ks);
    __builtin_amdgcn_s_barrier();
    __builtin_amdgcn_s_setprio(1);
#pragma unroll
    for (int m = 0; m < 4; m++)
#pragma unroll
      for (int nf = 0; nf < 2; nf++)
#pragma unroll
        for (int ks = 0; ks < 2; ks++)
          acc[m + 4][nf] = __builtin_amdgcn_mfma_f32_16x16x32_bf16(afr[m][ks], bfr[nf][ks], acc[m + 4][nf], 0, 0, 0);
    __builtin_amdgcn_s_setprio(0);
    // tile boundary: ensure tile t+1 resident (allow t+2's 6 loads in flight)
    if (t + 2 < NT) { asm volatile("s_waitcnt vmcnt(6)" ::: "memory"); }
    else            { asm volatile("s_waitcnt vmcnt(0)" ::: "memory"); }
    __builtin_amdgcn_s_barrier();
  }
#undef STAGE
#undef LDA
#undef LDB

  // ---- epilogue: C/D layout (m89): col = lane&15, row = (lane>>4)*4 + reg ----
  if (FIRST) {
    float bv[2];
#pragma unroll
    for (int nf = 0; nf < 2; nf++) bv[nf] = bias[e * NC + n0 + (wcol << 5) + (nf << 4) + fr];
#pragma unroll
    for (int m = 0; m < 8; m++) {
#pragma unroll
      for (int r2 = 0; r2 < 4; r2++) {
        int row = row0 + (wrow << 7) + (m << 4) + ((lane >> 4) << 2) + r2;
#pragma unroll
        for (int nf = 0; nf < 2; nf++) {
          int col = n0 + (wcol << 5) + (nf << 4) + fr;
          float x = acc[m][nf][r2] + bv[nf];
          float g = 0.5f * x * (1.0f + erff(x * 0.70710678118654752f));  // exact GELU
          hbuf[(size_t)row * NC + col] = f32_to_bf16(g);
        }
      }
    }
  } else {
    float bv[2];
#pragma unroll
    for (int nf = 0; nf < 2; nf++)
      bv[nf] = (blockIdx.z == 0) ? bias[e * NC + n0 + (wcol << 5) + (nf << 4) + fr] : 0.f;
#pragma unroll
    for (int m = 0; m < 8; m++) {
#pragma unroll
      for (int r2 = 0; r2 < 4; r2++) {
        int row = row0 + (wrow << 7) + (m << 4) + ((lane >> 4) << 2) + r2;
        int tdst = cidx[row];
        float cw = cwgt[row];
        if (tdst >= 0) {
#pragma unroll
          for (int nf = 0; nf < 2; nf++) {
            int col = n0 + (wcol << 5) + (nf << 4) + fr;
            atomicAdd(outp + (size_t)tdst * NC + col, cw * (acc[m][nf][r2] + bv[nf]));
          }
        }
      }
    }
  }
}

extern "C" void kernel_launch(void* const* d_in, const int* in_sizes, int n_in,
                              void* d_out, int out_size, void* d_ws, size_t ws_size,
                              hipStream_t stream) {
  const float* hidden = (const float*)d_in[0];
  const float* ew     = (const float*)d_in[1];
  const float* W1     = (const float*)d_in[2];
  const float* b1     = (const float*)d_in[3];
  const float* W2     = (const float*)d_in[4];
  const float* b2     = (const float*)d_in[5];
  const int*   sel    = (const int*)d_in[6];
  float* outp = (float*)d_out;

  // workspace layout (~217 MB)
  unsigned short* hbf  = (unsigned short*)d_ws;                  // [T][H] bf16        8 MB
  unsigned short* W1T  = hbf + (size_t)Td * Hd;                  // [E][F][H] bf16    64 MB
  unsigned short* W2T  = W1T + (size_t)Ed * Fd * Hd;             // [E][H][F] bf16    64 MB
  unsigned short* hbuf = W2T + (size_t)Ed * Hd * Fd;             // [Rcap][F] bf16    80 MB
  int*   idxT = (int*)(hbuf + (size_t)Rcap * Fd);
  float* wgtT = (float*)(idxT + Ed * Td);
  int*   off  = (int*)(wgtT + Ed * Td);
  int*   cidx = off + 16;
  float* cwgt = (float*)(cidx + Rcap);

  constexpr int LDS_BYTES = 147456;
  (void)hipFuncSetAttribute((const void*)gemm_kernel<true, Hd, Fd, 1>,
                            hipFuncAttributeMaxDynamicSharedMemorySize, LDS_BYTES);
  (void)hipFuncSetAttribute((const void*)gemm_kernel<false, Fd, Hd, 2>,
                            hipFuncAttributeMaxDynamicSharedMemorySize, LDS_BYTES);

  (void)hipMemsetAsync(d_out, 0, (size_t)Td * Hd * sizeof(float), stream);

  cvt_bf16_kernel<<<(Td * Hd / 8 + 255) / 256, 256, 0, stream>>>(hidden, hbf, Td * Hd / 8);
  transpose_cvt_kernel<<<Ed * (Hd / 64) * (Fd / 64), 256, 0, stream>>>(W1, W1T, Hd, Fd);
  transpose_cvt_kernel<<<Ed * (Fd / 64) * (Hd / 64), 256, 0, stream>>>(W2, W2T, Fd, Hd);

  route_all_kernel<<<1, 1024, 0, stream>>>(sel, ew, idxT, wgtT, off, cidx, cwgt);

  gemm_kernel<true, Hd, Fd, 1><<<dim3(Rcap / 256, Fd / 128, 1), 512, LDS_BYTES, stream>>>(
      hbf, W1T, b1, cidx, cwgt, off, hbuf, nullptr);
  gemm_kernel<false, Fd, Hd, 2><<<dim3(Rcap / 256, Hd / 128, 2), 512, LDS_BYTES, stream>>>(
      hbuf, W2T, b2, cidx, cwgt, off, nullptr, outp);
}

// Round 5
// 589.038 us; speedup vs baseline: 1.1752x; 1.1184x over previous
//
#include <hip/hip_runtime.h>
#include <hip/hip_bf16.h>

// Problem dims (fixed by the reference)
#define Td 4096    // tokens
#define Hd 1024    // hidden
#define Fd 4096    // ffn
#define Ed 8       // experts
#define Rcap 10240 // 40*256 compacted-row capacity (>= 8192 + 8*255, padded to 256)

typedef __attribute__((ext_vector_type(8))) short bf16x8;   // MFMA A/B frag (4 VGPRs)
typedef __attribute__((ext_vector_type(4))) float f32x4;    // MFMA C/D frag
typedef __attribute__((ext_vector_type(8))) unsigned short u16x8;

__device__ __forceinline__ unsigned short f32_to_bf16(float x) {
  unsigned int u = __float_as_uint(x);
  unsigned int r = (u + 0x7FFFu + ((u >> 16) & 1u)) >> 16;
  return (unsigned short)r;
}

// async global->LDS, 16B per lane. LDS dest is wave-uniform base + lane*16.
__device__ __forceinline__ void gload_lds16(const unsigned short* g, unsigned short* l) {
  __builtin_amdgcn_global_load_lds(
      (const __attribute__((address_space(1))) unsigned int*)g,
      (__attribute__((address_space(3))) unsigned int*)l, 16, 0, 0);
}

// ---------------- hidden f32 -> bf16 ----------------
__global__ __launch_bounds__(256) void cvt_bf16_kernel(const float* __restrict__ in,
                                                       unsigned short* __restrict__ outp, int n8) {
  int i = blockIdx.x * 256 + threadIdx.x;
  if (i >= n8) return;
  const float4* p = (const float4*)(in + (size_t)i * 8);
  float4 a = p[0], b = p[1];
  u16x8 o;
  o[0] = f32_to_bf16(a.x); o[1] = f32_to_bf16(a.y); o[2] = f32_to_bf16(a.z); o[3] = f32_to_bf16(a.w);
  o[4] = f32_to_bf16(b.x); o[5] = f32_to_bf16(b.y); o[6] = f32_to_bf16(b.z); o[7] = f32_to_bf16(b.w);
  *(u16x8*)(outp + (size_t)i * 8) = o;
}

// ---------------- weight transpose+convert: in [E][Rd][Cd] f32 -> out [E][Cd][Rd] bf16 ----------------
__global__ __launch_bounds__(256) void transpose_cvt_kernel(const float* __restrict__ in,
                                                            unsigned short* __restrict__ outp,
                                                            int Rdm, int Cdm) {
  __shared__ float tile[64][68];
  int tilesR = Rdm >> 6, tilesC = Cdm >> 6;
  int per = tilesR * tilesC;
  int bid = blockIdx.x;
  int e = bid / per; int rem = bid - e * per;
  int tr = rem / tilesC; int tc = rem - tr * tilesC;
  int r0 = tr << 6, c0 = tc << 6;
  int tid = threadIdx.x;
  int rr = tid >> 2, cq = (tid & 3) << 4;
  const float* src = in + ((size_t)e * Rdm + r0 + rr) * Cdm + c0 + cq;
  float4 v0 = ((const float4*)src)[0];
  float4 v1 = ((const float4*)src)[1];
  float4 v2 = ((const float4*)src)[2];
  float4 v3 = ((const float4*)src)[3];
  *(float4*)&tile[rr][cq + 0]  = v0;
  *(float4*)&tile[rr][cq + 4]  = v1;
  *(float4*)&tile[rr][cq + 8]  = v2;
  *(float4*)&tile[rr][cq + 12] = v3;
  __syncthreads();
  u16x8 o0, o1;
#pragma unroll
  for (int j = 0; j < 8; j++) o0[j] = f32_to_bf16(tile[cq + j][rr]);
#pragma unroll
  for (int j = 0; j < 8; j++) o1[j] = f32_to_bf16(tile[cq + 8 + j][rr]);
  unsigned short* dst = outp + ((size_t)e * Cdm + c0 + rr) * Rdm + r0 + cq;
  *(u16x8*)dst = o0;
  *(u16x8*)(dst + 8) = o1;
}

// ---------------- routing: count + scan + compact + per-token row/weight records ----------------
__global__ __launch_bounds__(1024) void route_all_kernel(const int* __restrict__ sel,
                                                         const float* __restrict__ ew,
                                                         int* __restrict__ idxT,
                                                         int* __restrict__ off_g,
                                                         int* __restrict__ cidx,
                                                         int2* __restrict__ trow,
                                                         float2* __restrict__ twgt) {
  __shared__ int cnt[Ed];
  __shared__ int off[Ed + 1];
  int tid = threadIdx.x;
  if (tid < Ed) cnt[tid] = 0;
  __syncthreads();
  int2 pks[Td / 1024];
#pragma unroll
  for (int k = 0; k < Td / 1024; k++) {
    int t = tid + (k << 10);
    int e0 = sel[2 * t], e1 = sel[2 * t + 1];
    float w0 = ew[2 * t], w1 = ew[2 * t + 1];
    if (e0 == e1) { w0 += w1; e1 = -1; }  // merge duplicate expert
    int2 pk = make_int2(-1, -1);
    if (e0 >= 0 && e0 < Ed) { int p = atomicAdd(&cnt[e0], 1); idxT[e0 * Td + p] = t; pk.x = (p << 3) | e0; }
    if (e1 >= 0 && e1 < Ed) { int p = atomicAdd(&cnt[e1], 1); idxT[e1 * Td + p] = t; pk.y = (p << 3) | e1; }
    pks[k] = pk;
    twgt[t] = make_float2(w0, w1);
  }
  __syncthreads();
  if (tid == 0) {
    int a = 0; off[0] = 0;
#pragma unroll
    for (int e = 0; e < Ed; e++) { a += (cnt[e] + 255) & ~255; off[e + 1] = a; }
  }
  __syncthreads();
#pragma unroll
  for (int k = 0; k < Td / 1024; k++) {
    int t = tid + (k << 10);
    int2 pk = pks[k];
    int2 r;
    r.x = (pk.x >= 0) ? off[pk.x & 7] + (pk.x >> 3) : -1;
    r.y = (pk.y >= 0) ? off[pk.y & 7] + (pk.y >> 3) : -1;
    trow[t] = r;
  }
  for (int j = tid; j < Ed * Td; j += 1024) {
    int e = j >> 12, i = j & (Td - 1);
    int row = off[e] + i;
    if (row < off[e + 1]) cidx[row] = (i < cnt[e]) ? idxT[e * Td + i] : -1;
  }
  if (tid <= Ed) off_g[tid] = off[tid];
}

// ---------------- pipelined MFMA GEMM ----------------
// BM=256, BN=128, BK=64, 8 waves as 4(row)x2(col): wave owns 64x64 (4m x 4n frags).
// LDS: 3 buffers x (A 32KB + B 16KB) = 144 KB; stage tile t+2 split 3+3 stmts across t's 2 phases.
// Counted s_waitcnt vmcnt(6) at tile boundary (only t+2's 6 stmts in flight; FIFO => t+1 resident).
// Phase = {8 ds_read_b128 ; 3 gload stmts ; s_barrier ; setprio(1) 16 MFMA setprio(0) ; [vmcnt] ; s_barrier}.
// T2 XOR swizzle kbyte ^= (row&7)<<4 via inverse-swizzled global source (verified: 0 bank conflicts r3).
// XCD mapping (MAP): assumes hw xcd = blockIdx.x % 8.
//  MAP0 (GEMM1): xcd owns 4 n-tiles (512-col chunk; per-expert B-slab 1MB -> L2-resident), m sweeps 0..39.
//  MAP1 (GEMM2): xcd owns 5 m-tiles; n cycles inner (A-panel 2MB reused x8 from L2).
// FIRST:  A = hbf gathered by cidx, B = W1T[e][F][H]; out = gelu(A*B + b1) -> hbuf (bf16)
// !FIRST: A = hbuf rows,            B = W2T[e][H][F]; y[row] = A*B + b2 (f32)
template <bool FIRST, int KD, int NC, int MAP>
__global__ __launch_bounds__(512, 1) void gemm_kernel(const unsigned short* __restrict__ Abase,
                                                      const unsigned short* __restrict__ Bt,
                                                      const float* __restrict__ bias,
                                                      const int* __restrict__ cidx,
                                                      const int* __restrict__ off,
                                                      unsigned short* __restrict__ hbuf,
                                                      float* __restrict__ yout) {
  extern __shared__ unsigned short lds[];   // 3*16384 (A) + 3*8192 (B) elems = 147456 B
  constexpr int NT = KD / 64;

  // ---- XCD-aware decode ----
  const int xcd = blockIdx.x & 7, slot = blockIdx.x >> 3;
  int mt, nt;
  if (MAP == 0) { nt = (xcd << 2) + (slot & 3); mt = slot >> 2; }
  else          { nt = slot & 7;                mt = xcd * 5 + (slot >> 3); }
  const int row0 = mt << 8;
  const int tot = off[Ed];
  if (row0 >= tot) return;                 // uniform exit, before any barrier
  int e = 0;
  while (off[e + 1] <= row0) ++e;          // 256-padded: tile never spans experts
  const int n0 = nt << 7;

  const int tid = threadIdx.x;
  const int lane = tid & 63, w = tid >> 6;
  const int wrow = w >> 1, wcol = w & 1;   // 4x2 wave grid, wave tile 64x64
  const int fr = lane & 15;
  const int fkb = (lane >> 4) << 4;        // frag k-byte sub-offset (0,16,32,48)

  // ---- stage source pointers (inverse-swizzled global; linear LDS dest + swizzled read) ----
  const unsigned short* aptr[4];
#pragma unroll
  for (int i = 0; i < 4; i++) {
    int r = (i << 6) + (tid >> 3);                         // 0..255
    int kel = ((tid & 7) ^ (r & 7)) << 3;                  // pre-swizzled element offset
    int g;
    if (FIRST) { g = cidx[row0 + r]; if (g < 0) g = 0; }   // clamp: garbage confined to dead rows
    else       { g = row0 + r; }
    aptr[i] = Abase + (size_t)g * KD + kel;
  }
  const unsigned short* bptr[2];
#pragma unroll
  for (int i = 0; i < 2; i++) {
    int r = (i << 6) + (tid >> 3);                         // 0..127
    int kel = ((tid & 7) ^ (r & 7)) << 3;
    bptr[i] = Bt + ((size_t)e * NC + n0 + r) * KD + kel;
  }
  unsigned short* ldsA = lds;              // 3 bufs x 16384 elems
  unsigned short* ldsB = lds + 49152;      // 3 bufs x 8192 elems

  f32x4 acc[4][4] = {};

  // stage half ph (0/1) of tile t: ph0 = {A rows 0-127, B rows 0-63}, ph1 = {A 128-255, B 64-127}
#define STAGE_P(t, ph)                                                              \
  {                                                                                 \
    const int _b = (t) % 3; const int _k0 = (t) << 6;                               \
    unsigned short* _la = ldsA + (_b << 14) + ((ph) << 13) + (w << 9);              \
    unsigned short* _lb = ldsB + (_b << 13) + ((ph) << 12) + (w << 9);              \
    gload_lds16(aptr[(ph) * 2 + 0] + _k0, _la);                                     \
    gload_lds16(aptr[(ph) * 2 + 1] + _k0, _la + 4096);                              \
    gload_lds16(bptr[(ph)] + _k0, _lb);                                             \
  }

  // swizzled frag reads: logical (row r, kbyte kb) -> physical kb ^ ((r&7)<<4)
#define LDA(dst, buf, m, ks)                                                        \
  {                                                                                 \
    int _r = (wrow << 6) + ((m) << 4) + fr;                                         \
    int _p = (((ks) << 6) + fkb) ^ ((_r & 7) << 4);                                 \
    dst = *(const bf16x8*)(ldsA + ((buf) << 14) + (_r << 6) + (_p >> 1));           \
  }
#define LDB(dst, buf, nf, ks)                                                       \
  {                                                                                 \
    int _r = (wcol << 6) + ((nf) << 4) + fr;                                        \
    int _p = (((ks) << 6) + fkb) ^ ((_r & 7) << 4);                                 \
    dst = *(const bf16x8*)(ldsB + ((buf) << 13) + (_r << 6) + (_p >> 1));           \
  }

  // prologue: stage tiles 0 and 1 fully; wait tile 0 (allow tile 1's 6 stmts in flight)
  STAGE_P(0, 0); STAGE_P(0, 1);
  STAGE_P(1, 0); STAGE_P(1, 1);
  asm volatile("s_waitcnt vmcnt(6)" ::: "memory");
  __builtin_amdgcn_s_barrier();

  for (int t = 0; t < NT; ++t) {
    const int buf = t % 3;
    // ---- phase 0 (ks=0) ----
    {
      bf16x8 af[4], bfr[4];
#pragma unroll
      for (int m = 0; m < 4; m++) LDA(af[m], buf, m, 0);
#pragma unroll
      for (int n = 0; n < 4; n++) LDB(bfr[n], buf, n, 0);
      if (t + 2 < NT) STAGE_P(t + 2, 0);
      __builtin_amdgcn_s_barrier();
      __builtin_amdgcn_s_setprio(1);
#pragma unroll
      for (int m = 0; m < 4; m++)
#pragma unroll
        for (int n = 0; n < 4; n++)
          acc[m][n] = __builtin_amdgcn_mfma_f32_16x16x32_bf16(af[m], bfr[n], acc[m][n], 0, 0, 0);
      __builtin_amdgcn_s_setprio(0);
      __builtin_amdgcn_s_barrier();
    }
    // ---- phase 1 (ks=1) ----
    {
      bf16x8 af[4], bfr[4];
#pragma unroll
      for (int m = 0; m < 4; m++) LDA(af[m], buf, m, 1);
#pragma unroll
      for (int n = 0; n < 4; n++) LDB(bfr[n], buf, n, 1);
      if (t + 2 < NT) STAGE_P(t + 2, 1);
      __builtin_amdgcn_s_barrier();
      __builtin_amdgcn_s_setprio(1);
#pragma unroll
      for (int m = 0; m < 4; m++)
#pragma unroll
        for (int n = 0; n < 4; n++)
          acc[m][n] = __builtin_amdgcn_mfma_f32_16x16x32_bf16(af[m], bfr[n], acc[m][n], 0, 0, 0);
      __builtin_amdgcn_s_setprio(0);
      // tile boundary: tile t+1 must be resident; only t+2's 6 stmts may remain in flight
      if (t + 2 < NT) { asm volatile("s_waitcnt vmcnt(6)" ::: "memory"); }
      else            { asm volatile("s_waitcnt vmcnt(0)" ::: "memory"); }
      __builtin_amdgcn_s_barrier();
    }
  }
#undef STAGE_P
#undef LDA
#undef LDB

  // ---- epilogue: C/D layout (m89): col = lane&15, row = (lane>>4)*4 + reg ----
  float bv[4];
#pragma unroll
  for (int n = 0; n < 4; n++) bv[n] = bias[e * NC + n0 + (wcol << 6) + (n << 4) + fr];
#pragma unroll
  for (int m = 0; m < 4; m++) {
#pragma unroll
    for (int r2 = 0; r2 < 4; r2++) {
      int row = row0 + (wrow << 6) + (m << 4) + ((lane >> 4) << 2) + r2;
#pragma unroll
      for (int n = 0; n < 4; n++) {
        int col = n0 + (wcol << 6) + (n << 4) + fr;
        float x = acc[m][n][r2] + bv[n];
        if (FIRST) {
          float g = 0.5f * x * (1.0f + erff(x * 0.70710678118654752f));  // exact GELU
          hbuf[(size_t)row * NC + col] = f32_to_bf16(g);
        } else {
          yout[(size_t)row * NC + col] = x;
        }
      }
    }
  }
}

// ---------------- final combine: out[t] = cw0*y[r0] + cw1*y[r1] ----------------
__global__ __launch_bounds__(256) void combine_kernel(const float* __restrict__ y,
                                                      const int2* __restrict__ trow,
                                                      const float2* __restrict__ twgt,
                                                      float* __restrict__ outp) {
  int t = blockIdx.x, hq = threadIdx.x;           // Hd/4 = 256 float4 per token
  int2 r = trow[t];
  float2 wv = twgt[t];
  const float4* y4 = (const float4*)y;
  float4 a = make_float4(0.f, 0.f, 0.f, 0.f);
  if (r.x >= 0) {
    float4 v = y4[(size_t)r.x * (Hd / 4) + hq];
    a.x = wv.x * v.x; a.y = wv.x * v.y; a.z = wv.x * v.z; a.w = wv.x * v.w;
  }
  if (r.y >= 0) {
    float4 v = y4[(size_t)r.y * (Hd / 4) + hq];
    a.x += wv.y * v.x; a.y += wv.y * v.y; a.z += wv.y * v.z; a.w += wv.y * v.w;
  }
  ((float4*)outp)[(size_t)t * (Hd / 4) + hq] = a;
}

extern "C" void kernel_launch(void* const* d_in, const int* in_sizes, int n_in,
                              void* d_out, int out_size, void* d_ws, size_t ws_size,
                              hipStream_t stream) {
  const float* hidden = (const float*)d_in[0];
  const float* ew     = (const float*)d_in[1];
  const float* W1     = (const float*)d_in[2];
  const float* b1     = (const float*)d_in[3];
  const float* W2     = (const float*)d_in[4];
  const float* b2     = (const float*)d_in[5];
  const int*   sel    = (const int*)d_in[6];
  float* outp = (float*)d_out;

  // workspace layout (~217 MB)
  unsigned short* hbf  = (unsigned short*)d_ws;                  // [T][H] bf16        8 MB
  unsigned short* W1T  = hbf + (size_t)Td * Hd;                  // [E][F][H] bf16    64 MB
  unsigned short* W2T  = W1T + (size_t)Ed * Fd * Hd;             // [E][H][F] bf16    64 MB
  unsigned short* hbuf = W2T + (size_t)Ed * Hd * Fd;             // [Rcap][F] bf16    80 MB
  int*    idxT = (int*)(hbuf + (size_t)Rcap * Fd);
  int*    off  = idxT + Ed * Td;
  int*    cidx = off + 16;
  int2*   trow = (int2*)(cidx + Rcap);
  float2* twgt = (float2*)(trow + Td);
  // y (f32, 42 MB) aliases W1T's region: W1T fully consumed by GEMM1 before GEMM2 writes y.
  float*  y    = (float*)W1T;

  constexpr int LDS_BYTES = 147456;
  (void)hipFuncSetAttribute((const void*)gemm_kernel<true, Hd, Fd, 0>,
                            hipFuncAttributeMaxDynamicSharedMemorySize, LDS_BYTES);
  (void)hipFuncSetAttribute((const void*)gemm_kernel<false, Fd, Hd, 1>,
                            hipFuncAttributeMaxDynamicSharedMemorySize, LDS_BYTES);

  cvt_bf16_kernel<<<(Td * Hd / 8 + 255) / 256, 256, 0, stream>>>(hidden, hbf, Td * Hd / 8);
  transpose_cvt_kernel<<<Ed * (Hd / 64) * (Fd / 64), 256, 0, stream>>>(W1, W1T, Hd, Fd);
  transpose_cvt_kernel<<<Ed * (Fd / 64) * (Hd / 64), 256, 0, stream>>>(W2, W2T, Fd, Hd);

  route_all_kernel<<<1, 1024, 0, stream>>>(sel, ew, idxT, off, cidx, trow, twgt);

  // GEMM1: grid 40m x 32n = 1280 = 8 xcd x 160 slots (4 n-tiles/xcd chunk)
  gemm_kernel<true, Hd, Fd, 0><<<1280, 512, LDS_BYTES, stream>>>(
      hbf, W1T, b1, cidx, off, hbuf, nullptr);
  // GEMM2: grid 40m x 8n = 320 = 8 xcd x 40 slots (5 m-tiles/xcd chunk, n inner)
  gemm_kernel<false, Fd, Hd, 1><<<320, 512, LDS_BYTES, stream>>>(
      hbuf, W2T, b2, cidx, off, nullptr, y);

  combine_kernel<<<Td, 256, 0, stream>>>(y, trow, twgt, outp);
}